// Round 1
// baseline (92.724 us; speedup 1.0000x reference)
//
#include <hip/hip_runtime.h>

// Problem constants (ConvexReLUCNN): B=512, C=3, H=W=64, KERNEL=3
//   K = 27, L = 62*62 = 3844, M = 512, O = 10
#define M_NEUR 512
#define KDIM   27
#define ODIM   10
#define HO     62
#define LDIM   3844      // 62*62
#define CHW    12288     // 3*64*64
#define BATCH  512
#define KO     (KDIM*ODIM)   // 270

// ---------------------------------------------------------------------------
// K1: T[(k*10+o)*3844 + n] = sum_m G[m*3844+n] * (v[m*270+k*10+o] - w[...])
// grid (16, 27), block 256. Each thread: one n, all 10 o's, full m loop.
// pd slice for this k staged in LDS (stride 12 for 16B-aligned float4 reads).
// ---------------------------------------------------------------------------
__global__ __launch_bounds__(256)
void t_gemm_kernel(const float* __restrict__ G,
                   const float* __restrict__ v,
                   const float* __restrict__ w,
                   float* __restrict__ T) {
    const int k = blockIdx.y;
    const int n = blockIdx.x * 256 + threadIdx.x;
    const int nc = (n < LDIM) ? n : (LDIM - 1);

    __shared__ float pd[M_NEUR * 12];
    for (int t = threadIdx.x; t < M_NEUR * ODIM; t += 256) {
        int m = t / ODIM;
        int o = t - m * ODIM;
        int src = m * KO + k * ODIM + o;
        pd[m * 12 + o] = v[src] - w[src];
    }
    __syncthreads();

    float acc[ODIM];
#pragma unroll
    for (int o = 0; o < ODIM; ++o) acc[o] = 0.f;

    const float* gp = G + nc;
#pragma unroll 4
    for (int m = 0; m < M_NEUR; ++m) {
        float g = gp[(size_t)m * LDIM];
        const float4* p = reinterpret_cast<const float4*>(&pd[m * 12]);
        float4 a = p[0];
        float4 b = p[1];
        float2 c = *reinterpret_cast<const float2*>(&pd[m * 12 + 8]);
        acc[0] += g * a.x;  acc[1] += g * a.y;
        acc[2] += g * a.z;  acc[3] += g * a.w;
        acc[4] += g * b.x;  acc[5] += g * b.y;
        acc[6] += g * b.z;  acc[7] += g * b.w;
        acc[8] += g * c.x;  acc[9] += g * c.y;
    }

    if (n < LDIM) {
#pragma unroll
        for (int o = 0; o < ODIM; ++o)
            T[(size_t)(k * ODIM + o) * LDIM + n] = acc[o];
    }
}

// ---------------------------------------------------------------------------
// K2: fold T (k,o,n) -> S[o][c*4096 + h*64 + w]
//   S[c,h,w,o] = sum_{i,j in 0..2, (h-i),(w-j) in [0,62)} T[(c*9+i*3+j)*10+o][(h-i)*62+(w-j)]
// 12288 threads total.
// ---------------------------------------------------------------------------
__global__ __launch_bounds__(256)
void fold_kernel(const float* __restrict__ T, float* __restrict__ S) {
    int idx = blockIdx.x * 256 + threadIdx.x;   // chw index
    int c = idx >> 12;
    int h = (idx >> 6) & 63;
    int w = idx & 63;

    float s[ODIM];
#pragma unroll
    for (int o = 0; o < ODIM; ++o) s[o] = 0.f;

    for (int i = 0; i < 3; ++i) {
        int pi = h - i;
        if ((unsigned)pi >= HO) continue;
        for (int j = 0; j < 3; ++j) {
            int pj = w - j;
            if ((unsigned)pj >= HO) continue;
            int kk = c * 9 + i * 3 + j;
            const float* tp = T + (size_t)kk * ODIM * LDIM + pi * HO + pj;
#pragma unroll
            for (int o = 0; o < ODIM; ++o) s[o] += tp[(size_t)o * LDIM];
        }
    }
#pragma unroll
    for (int o = 0; o < ODIM; ++o) S[o * CHW + idx] = s[o];
}

// ---------------------------------------------------------------------------
// K3: out[b][o] = sum_{chw} x[b][chw] * S[o][chw]
// grid 128 blocks, 4 batches per block, float4 loads, wave+LDS reduction.
// ---------------------------------------------------------------------------
__global__ __launch_bounds__(256)
void out_gemm_kernel(const float* __restrict__ X,
                     const float* __restrict__ S,
                     float* __restrict__ out) {
    const int b0 = blockIdx.x * 4;
    const int tid = threadIdx.x;
    const int NV = CHW / 4;   // 3072 float4s per image
    const float4* X4 = reinterpret_cast<const float4*>(X);
    const float4* S4 = reinterpret_cast<const float4*>(S);

    float acc[4][ODIM];
#pragma unroll
    for (int bt = 0; bt < 4; ++bt)
#pragma unroll
        for (int o = 0; o < ODIM; ++o) acc[bt][o] = 0.f;

    for (int i = tid; i < NV; i += 256) {
        float4 xv[4];
#pragma unroll
        for (int bt = 0; bt < 4; ++bt)
            xv[bt] = X4[(size_t)(b0 + bt) * NV + i];
#pragma unroll
        for (int o = 0; o < ODIM; ++o) {
            float4 sv = S4[(size_t)o * NV + i];
#pragma unroll
            for (int bt = 0; bt < 4; ++bt) {
                acc[bt][o] += xv[bt].x * sv.x + xv[bt].y * sv.y
                            + xv[bt].z * sv.z + xv[bt].w * sv.w;
            }
        }
    }

    // intra-wave butterfly reduce (64 lanes)
#pragma unroll
    for (int bt = 0; bt < 4; ++bt)
#pragma unroll
        for (int o = 0; o < ODIM; ++o) {
            float s = acc[bt][o];
            for (int off = 32; off > 0; off >>= 1)
                s += __shfl_down(s, off, 64);
            acc[bt][o] = s;
        }

    __shared__ float red[4][40];
    int wave = tid >> 6;
    int lane = tid & 63;
    if (lane == 0) {
#pragma unroll
        for (int bt = 0; bt < 4; ++bt)
#pragma unroll
            for (int o = 0; o < ODIM; ++o)
                red[wave][bt * ODIM + o] = acc[bt][o];
    }
    __syncthreads();
    if (tid < 40) {
        float t = red[0][tid] + red[1][tid] + red[2][tid] + red[3][tid];
        int bt = tid / ODIM;
        int o  = tid - bt * ODIM;
        out[(b0 + bt) * ODIM + o] = t;
    }
}

extern "C" void kernel_launch(void* const* d_in, const int* in_sizes, int n_in,
                              void* d_out, int out_size, void* d_ws, size_t ws_size,
                              hipStream_t stream) {
    const float* x = (const float*)d_in[0];   // (512, 3, 64, 64)
    const float* G = (const float*)d_in[1];   // (512, 3844)
    const float* v = (const float*)d_in[2];   // (512, 27, 10)
    const float* w = (const float*)d_in[3];   // (512, 27, 10)
    float* out = (float*)d_out;               // (512, 10)

    float* T = (float*)d_ws;                  // 270*3844 floats = 4.15 MB
    float* S = T + (size_t)KO * LDIM;         // 10*12288 floats = 0.49 MB

    dim3 g1((LDIM + 255) / 256, KDIM);        // (16, 27)
    t_gemm_kernel<<<g1, 256, 0, stream>>>(G, v, w, T);

    fold_kernel<<<CHW / 256, 256, 0, stream>>>(T, S);

    out_gemm_kernel<<<BATCH / 4, 256, 0, stream>>>(x, S, out);
}

// Round 2
// 69.344 us; speedup vs baseline: 1.3371x; 1.3371x over previous
//
#include <hip/hip_runtime.h>

// ConvexReLUCNN: B=512, C=3, H=W=64, KERNEL=3
//   K=27, L=62*62=3844, M=512, O=10
#define M_NEUR 512
#define KDIM   27
#define ODIM   10
#define HO     62
#define LDIM   3844
#define CHW    12288
#define BATCH  512
#define KO     (KDIM*ODIM)   // 270
#define PDSTR  16            // padded o-stride in pdw

// ---------------------------------------------------------------------------
// K0: pdw[k][m][o] = v[m][k][o] - w[m][k][o], padded stride 16 for s_load.
// ---------------------------------------------------------------------------
__global__ __launch_bounds__(256)
void pd_kernel(const float* __restrict__ v, const float* __restrict__ w,
               float* __restrict__ pdw) {
    int idx = blockIdx.x * 256 + threadIdx.x;      // over m*270+k*10+o
    if (idx >= M_NEUR * KO) return;
    int m = idx / KO;
    int r = idx - m * KO;
    int k = r / ODIM;
    int o = r - k * ODIM;
    pdw[((size_t)k * M_NEUR + m) * PDSTR + o] = v[idx] - w[idx];
}

// ---------------------------------------------------------------------------
// K1: T[(k*10+o)*3844 + n] = sum_m G[m*3844+n] * pdw[k][m][o]
// grid (31, 27), block (128, 4). threadIdx.y = m-chunk (128 m each).
// pdw read via wave-uniform address -> s_load; G via coalesced vector load.
// Cross-chunk reduction through LDS.
// ---------------------------------------------------------------------------
__global__ __launch_bounds__(512)
void t_gemm_kernel(const float* __restrict__ G,
                   const float* __restrict__ pdw,
                   float* __restrict__ T) {
    const int k    = blockIdx.y;
    const int tidx = threadIdx.x;            // 0..127
    const int mc   = threadIdx.y;            // 0..3
    const int n    = blockIdx.x * 128 + tidx;
    const int nc   = (n < LDIM) ? n : (LDIM - 1);

    // mc is constant within each wave (128 threads per mc-row = 2 waves);
    // force it scalar so pdw addresses are uniform -> s_load.
    const int mcs = __builtin_amdgcn_readfirstlane(mc);

    float acc[ODIM];
#pragma unroll
    for (int o = 0; o < ODIM; ++o) acc[o] = 0.f;

    const float* gp = G + (size_t)(mcs * 128) * LDIM + nc;
    const float* pr = pdw + ((size_t)k * M_NEUR + mcs * 128) * PDSTR;

#pragma unroll 8
    for (int m = 0; m < 128; ++m) {
        float g = gp[(size_t)m * LDIM];
        const float* p = pr + m * PDSTR;   // wave-uniform
        acc[0] += g * p[0];  acc[1] += g * p[1];
        acc[2] += g * p[2];  acc[3] += g * p[3];
        acc[4] += g * p[4];  acc[5] += g * p[5];
        acc[6] += g * p[6];  acc[7] += g * p[7];
        acc[8] += g * p[8];  acc[9] += g * p[9];
    }

    __shared__ float red[3][ODIM][128];
    if (mc > 0) {
#pragma unroll
        for (int o = 0; o < ODIM; ++o) red[mc - 1][o][tidx] = acc[o];
    }
    __syncthreads();
    if (mc == 0 && n < LDIM) {
#pragma unroll
        for (int o = 0; o < ODIM; ++o) {
            float s = acc[o] + red[0][o][tidx] + red[1][o][tidx] + red[2][o][tidx];
            T[(size_t)(k * ODIM + o) * LDIM + n] = s;
        }
    }
}

// ---------------------------------------------------------------------------
// K2: fold T (k,o,n) -> S[o][c*4096 + h*64 + w]
// ---------------------------------------------------------------------------
__global__ __launch_bounds__(256)
void fold_kernel(const float* __restrict__ T, float* __restrict__ S) {
    int idx = blockIdx.x * 256 + threadIdx.x;   // chw index
    int c = idx >> 12;
    int h = (idx >> 6) & 63;
    int w = idx & 63;

    float s[ODIM];
#pragma unroll
    for (int o = 0; o < ODIM; ++o) s[o] = 0.f;

    for (int i = 0; i < 3; ++i) {
        int pi = h - i;
        if ((unsigned)pi >= HO) continue;
        for (int j = 0; j < 3; ++j) {
            int pj = w - j;
            if ((unsigned)pj >= HO) continue;
            int kk = c * 9 + i * 3 + j;
            const float* tp = T + (size_t)kk * ODIM * LDIM + pi * HO + pj;
#pragma unroll
            for (int o = 0; o < ODIM; ++o) s[o] += tp[(size_t)o * LDIM];
        }
    }
#pragma unroll
    for (int o = 0; o < ODIM; ++o) S[o * CHW + idx] = s[o];
}

// ---------------------------------------------------------------------------
// K3: out[b][o] = sum_{chw} x[b][chw] * S[o][chw]
// 512 blocks (1 batch each), 256 threads, float4 loads.
// ---------------------------------------------------------------------------
__global__ __launch_bounds__(256)
void out_gemm_kernel(const float* __restrict__ X,
                     const float* __restrict__ S,
                     float* __restrict__ out) {
    const int b   = blockIdx.x;
    const int tid = threadIdx.x;
    const int NV  = CHW / 4;   // 3072
    const float4* X4 = reinterpret_cast<const float4*>(X) + (size_t)b * NV;
    const float4* S4 = reinterpret_cast<const float4*>(S);

    float acc[ODIM];
#pragma unroll
    for (int o = 0; o < ODIM; ++o) acc[o] = 0.f;

    for (int i = tid; i < NV; i += 256) {
        float4 xv = X4[i];
#pragma unroll
        for (int o = 0; o < ODIM; ++o) {
            float4 sv = S4[(size_t)o * NV + i];
            acc[o] += xv.x * sv.x + xv.y * sv.y + xv.z * sv.z + xv.w * sv.w;
        }
    }

#pragma unroll
    for (int o = 0; o < ODIM; ++o) {
        float s = acc[o];
        for (int off = 32; off > 0; off >>= 1)
            s += __shfl_down(s, off, 64);
        acc[o] = s;
    }

    __shared__ float red[4][ODIM];
    int wave = tid >> 6;
    int lane = tid & 63;
    if (lane == 0) {
#pragma unroll
        for (int o = 0; o < ODIM; ++o) red[wave][o] = acc[o];
    }
    __syncthreads();
    if (tid < ODIM) {
        out[(size_t)b * ODIM + tid] =
            red[0][tid] + red[1][tid] + red[2][tid] + red[3][tid];
    }
}

extern "C" void kernel_launch(void* const* d_in, const int* in_sizes, int n_in,
                              void* d_out, int out_size, void* d_ws, size_t ws_size,
                              hipStream_t stream) {
    const float* x = (const float*)d_in[0];   // (512, 3, 64, 64)
    const float* G = (const float*)d_in[1];   // (512, 3844)
    const float* v = (const float*)d_in[2];   // (512, 27, 10)
    const float* w = (const float*)d_in[3];   // (512, 27, 10)
    float* out = (float*)d_out;               // (512, 10)

    float* T   = (float*)d_ws;                         // 270*3844 f = 4.15 MB
    float* S   = T + (size_t)KO * LDIM;                // 10*12288 f = 0.49 MB
    float* pdw = S + (size_t)ODIM * CHW;               // 27*512*16 f = 0.88 MB

    pd_kernel<<<(M_NEUR * KO + 255) / 256, 256, 0, stream>>>(v, w, pdw);

    dim3 g1((LDIM + 127) / 128, KDIM);                 // (31, 27)
    t_gemm_kernel<<<g1, dim3(128, 4), 0, stream>>>(G, pdw, T);

    fold_kernel<<<CHW / 256, 256, 0, stream>>>(T, S);

    out_gemm_kernel<<<BATCH, 256, 0, stream>>>(x, S, out);
}

// Round 3
// 53.467 us; speedup vs baseline: 1.7342x; 1.2970x over previous
//
#include <hip/hip_runtime.h>

// ConvexReLUCNN: B=512, C=3, H=W=64, KERNEL=3
//   K=27, L=62*62=3844, M=512, O=10
#define M_NEUR 512
#define ODIM   10
#define HO     62
#define LDIM   3844
#define CHW    12288
#define BATCH  512
#define KO     270
#define PDS    20     // padded s-stride in pdY (17 used)

// ---------------------------------------------------------------------------
// K0: pack pd = v - w into pdY[(g*2+kg)][m][s] (s<17, pad 20), ko = 34g+kg+2s.
// Invalid slots (s>=17 or ko>=270) are zero-filled so fmacs are harmless.
// ---------------------------------------------------------------------------
__global__ __launch_bounds__(256)
void pd_kernel(const float* __restrict__ v, const float* __restrict__ w,
               float* __restrict__ pdY) {
    int idx = blockIdx.x * 256 + threadIdx.x;
    if (idx >= 16 * M_NEUR * PDS) return;
    int gk = idx / (M_NEUR * PDS);
    int r  = idx - gk * (M_NEUR * PDS);
    int m  = r / PDS;
    int s  = r - m * PDS;
    int g  = gk >> 1, kg = gk & 1;
    int ko = 34 * g + kg + 2 * s;
    float val = 0.f;
    if (s < 17 && ko < KO) {
        int src = m * KO + ko;
        val = v[src] - w[src];
    }
    pdY[idx] = val;
}

// ---------------------------------------------------------------------------
// K1: T[ko][n] = sum_m G[m][n] * pd[m][ko]
// 1D grid of 512 ids -> (t = n-tile 0..60, g = ko-group 0..7), mapped so all
// 8 g-blocks of a tile share id%8 (same XCD under round-robin dispatch -> the
// shared 128KB G-tile is fetched from HBM once, then L2-hit).
// Block 512 thr = 8 waves = 4 m-chunks x 2 ko-halves; wave-uniform pd base
// (readfirstlane) -> s_load_dwordx8; m-chunk reduce via LDS.
// ---------------------------------------------------------------------------
__global__ __launch_bounds__(512)
void t_gemm_kernel(const float* __restrict__ G,
                   const float* __restrict__ pdY,
                   float* __restrict__ T) {
    const int id = blockIdx.x;
    const int t  = (id & 7) + 8 * (id >> 6);   // n-tile
    const int g  = (id >> 3) & 7;              // ko-group
    if (t >= 61) return;

    const int tid  = threadIdx.x;
    const int lane = tid & 63;
    const int wv   = tid >> 6;          // 0..7
    const int mcw  = wv & 3;            // m-chunk (vector ctx for LDS)
    const int kg   = wv >> 2;           // ko-half
    const int sw   = __builtin_amdgcn_readfirstlane(wv);
    const int smc  = sw & 3;
    const int skg  = sw >> 2;

    const int n  = t * 64 + lane;
    const int nc = (n < LDIM) ? n : (LDIM - 1);

    float acc[17];
#pragma unroll
    for (int s = 0; s < 17; ++s) acc[s] = 0.f;

    const float* gp = G + (size_t)(smc * 128) * LDIM + nc;
    const float* pp = pdY + ((size_t)(g * 2 + skg) * M_NEUR + smc * 128) * PDS;

#pragma unroll 2
    for (int mi = 0; mi < 128; ++mi) {
        float gv = gp[(size_t)mi * LDIM];
        const float* p = pp + mi * PDS;   // wave-uniform -> s_load
#pragma unroll
        for (int s = 0; s < 17; ++s)
            acc[s] += gv * p[s];
    }

    __shared__ float red[3][2][17][64];
    if (mcw > 0) {
#pragma unroll
        for (int s = 0; s < 17; ++s) red[mcw - 1][kg][s][lane] = acc[s];
    }
    __syncthreads();
    if (mcw == 0 && n < LDIM) {
#pragma unroll
        for (int s = 0; s < 17; ++s) {
            int ko = 34 * g + kg + 2 * s;
            if (ko < KO) {
                float sum = acc[s] + red[0][kg][s][lane]
                          + red[1][kg][s][lane] + red[2][kg][s][lane];
                T[(size_t)ko * LDIM + n] = sum;
            }
        }
    }
}

// ---------------------------------------------------------------------------
// K2: fold T (ko, pix) -> S[o][c*4096 + h*64 + w]
// ---------------------------------------------------------------------------
__global__ __launch_bounds__(256)
void fold_kernel(const float* __restrict__ T, float* __restrict__ S) {
    int idx = blockIdx.x * 256 + threadIdx.x;   // chw index
    int c = idx >> 12;
    int h = (idx >> 6) & 63;
    int w = idx & 63;

    float s[ODIM];
#pragma unroll
    for (int o = 0; o < ODIM; ++o) s[o] = 0.f;

    for (int i = 0; i < 3; ++i) {
        int pi = h - i;
        if ((unsigned)pi >= HO) continue;
        for (int j = 0; j < 3; ++j) {
            int pj = w - j;
            if ((unsigned)pj >= HO) continue;
            int kk = c * 9 + i * 3 + j;
            const float* tp = T + (size_t)kk * ODIM * LDIM + pi * HO + pj;
#pragma unroll
            for (int o = 0; o < ODIM; ++o) s[o] += tp[(size_t)o * LDIM];
        }
    }
#pragma unroll
    for (int o = 0; o < ODIM; ++o) S[o * CHW + idx] = s[o];
}

// ---------------------------------------------------------------------------
// K3: out[b][o] = sum_chw x[b][chw] * S[o][chw]; 2 images/block, 256 blocks.
// ---------------------------------------------------------------------------
__global__ __launch_bounds__(256)
void out_gemm_kernel(const float* __restrict__ X,
                     const float* __restrict__ S,
                     float* __restrict__ out) {
    const int b0  = blockIdx.x * 2;
    const int tid = threadIdx.x;
    const int NV  = CHW / 4;   // 3072
    const float4* X0 = reinterpret_cast<const float4*>(X) + (size_t)b0 * NV;
    const float4* X1 = X0 + NV;
    const float4* S4 = reinterpret_cast<const float4*>(S);

    float acc0[ODIM], acc1[ODIM];
#pragma unroll
    for (int o = 0; o < ODIM; ++o) { acc0[o] = 0.f; acc1[o] = 0.f; }

    for (int i = tid; i < NV; i += 256) {
        float4 a = X0[i];
        float4 b = X1[i];
#pragma unroll
        for (int o = 0; o < ODIM; ++o) {
            float4 sv = S4[(size_t)o * NV + i];
            acc0[o] += a.x * sv.x + a.y * sv.y + a.z * sv.z + a.w * sv.w;
            acc1[o] += b.x * sv.x + b.y * sv.y + b.z * sv.z + b.w * sv.w;
        }
    }

#pragma unroll
    for (int o = 0; o < ODIM; ++o) {
        float s0 = acc0[o], s1 = acc1[o];
        for (int off = 32; off > 0; off >>= 1) {
            s0 += __shfl_down(s0, off, 64);
            s1 += __shfl_down(s1, off, 64);
        }
        acc0[o] = s0; acc1[o] = s1;
    }

    __shared__ float red[4][2 * ODIM];
    int wave = tid >> 6;
    int lane = tid & 63;
    if (lane == 0) {
#pragma unroll
        for (int o = 0; o < ODIM; ++o) {
            red[wave][o] = acc0[o];
            red[wave][ODIM + o] = acc1[o];
        }
    }
    __syncthreads();
    if (tid < 2 * ODIM) {
        float tsum = red[0][tid] + red[1][tid] + red[2][tid] + red[3][tid];
        int bt = tid / ODIM;
        int o  = tid - bt * ODIM;
        out[(size_t)(b0 + bt) * ODIM + o] = tsum;
    }
}

extern "C" void kernel_launch(void* const* d_in, const int* in_sizes, int n_in,
                              void* d_out, int out_size, void* d_ws, size_t ws_size,
                              hipStream_t stream) {
    const float* x = (const float*)d_in[0];   // (512, 3, 64, 64)
    const float* G = (const float*)d_in[1];   // (512, 3844)
    const float* v = (const float*)d_in[2];   // (512, 27, 10)
    const float* w = (const float*)d_in[3];   // (512, 27, 10)
    float* out = (float*)d_out;               // (512, 10)

    float* T   = (float*)d_ws;                       // 270*3844 f = 4.15 MB
    float* S   = T + (size_t)KO * LDIM;              // 10*12288 f = 0.49 MB
    float* pdY = S + (size_t)ODIM * CHW;             // 16*512*20 f = 0.66 MB

    pd_kernel<<<(16 * M_NEUR * PDS + 255) / 256, 256, 0, stream>>>(v, w, pdY);

    t_gemm_kernel<<<512, 512, 0, stream>>>(G, pdY, T);

    fold_kernel<<<CHW / 256, 256, 0, stream>>>(T, S);

    out_gemm_kernel<<<BATCH / 2, 256, 0, stream>>>(x, S, out);
}

// Round 4
// 51.820 us; speedup vs baseline: 1.7893x; 1.0318x over previous
//
#include <hip/hip_runtime.h>

// ConvexReLUCNN: B=512, C=3, H=W=64, KERNEL=3
//   K=27, L=62*62=3844, M=512, O=10
#define M_NEUR 512
#define ODIM   10
#define HO     62
#define LDIM   3844
#define CHW    12288
#define BATCH  512
#define KO     270
#define NG     16     // ko-groups
#define GS     17     // ko per group (16*17=272 >= 270, 2 pad)
#define PDS    24     // padded s-stride in pdY (17 used; 96B = 32B-aligned)

// ---------------------------------------------------------------------------
// K0: pack pd = v - w into pdY[g][m][s], ko = g*17+s. Zero-fill pad slots.
// ---------------------------------------------------------------------------
__global__ __launch_bounds__(256)
void pd_kernel(const float* __restrict__ v, const float* __restrict__ w,
               float* __restrict__ pdY) {
    int idx = blockIdx.x * 256 + threadIdx.x;      // over g*M*PDS
    if (idx >= NG * M_NEUR * PDS) return;
    int g = idx / (M_NEUR * PDS);
    int r = idx - g * (M_NEUR * PDS);
    int m = r / PDS;
    int s = r - m * PDS;
    int ko = g * GS + s;
    float val = 0.f;
    if (s < GS && ko < KO) {
        int src = m * KO + ko;
        val = v[src] - w[src];
    }
    pdY[idx] = val;
}

// ---------------------------------------------------------------------------
// K1: T[ko][n] = sum_m G[m][n] * pd[m][ko]
// Grid: 1024 ids -> (tile 0..60 of 64 n, g 0..15 of 17 ko); mapping keeps
// id%8 == tile%8 so all 16 g-blocks sharing a G-tile land on one XCD (the
// 128KB tile is HBM-fetched once, then L2-hit). Block 256 = 4 waves = 4
// m-chunks of 128; pd via wave-uniform s_load; cross-chunk reduce in LDS.
// ---------------------------------------------------------------------------
__global__ __launch_bounds__(256)
void t_gemm_kernel(const float* __restrict__ G,
                   const float* __restrict__ pdY,
                   float* __restrict__ T) {
    const int id    = blockIdx.x;
    const int r     = id & 7;
    const int inner = id >> 3;
    const int g     = inner & 15;
    const int tile  = (inner >> 4) * 8 + r;
    if (tile >= 61) return;

    const int tid  = threadIdx.x;
    const int lane = tid & 63;
    const int mc   = tid >> 6;                         // 0..3 (vector ctx)
    const int smc  = __builtin_amdgcn_readfirstlane(mc);

    const int n  = tile * 64 + lane;
    const int nc = (n < LDIM) ? n : (LDIM - 1);

    float acc[GS];
#pragma unroll
    for (int s = 0; s < GS; ++s) acc[s] = 0.f;

    const float* gp = G + (size_t)(smc * 128) * LDIM + nc;
    const float* pp = pdY + ((size_t)g * M_NEUR + smc * 128) * PDS;

#pragma unroll 4
    for (int mi = 0; mi < 128; ++mi) {
        float gv = gp[(size_t)mi * LDIM];
        const float* p = pp + mi * PDS;   // wave-uniform -> s_load
#pragma unroll
        for (int s = 0; s < GS; ++s)
            acc[s] += gv * p[s];
    }

    __shared__ float red[3][GS][64];
    if (mc > 0) {
#pragma unroll
        for (int s = 0; s < GS; ++s) red[mc - 1][s][lane] = acc[s];
    }
    __syncthreads();
    if (mc == 0 && n < LDIM) {
#pragma unroll
        for (int s = 0; s < GS; ++s) {
            int ko = g * GS + s;
            if (ko < KO) {
                float sum = acc[s] + red[0][s][lane]
                          + red[1][s][lane] + red[2][s][lane];
                T[(size_t)ko * LDIM + n] = sum;
            }
        }
    }
}

// ---------------------------------------------------------------------------
// K2: fold T (ko, pix) -> S[o][c*4096 + h*64 + w]
// ---------------------------------------------------------------------------
__global__ __launch_bounds__(256)
void fold_kernel(const float* __restrict__ T, float* __restrict__ S) {
    int idx = blockIdx.x * 256 + threadIdx.x;   // chw index
    int c = idx >> 12;
    int h = (idx >> 6) & 63;
    int w = idx & 63;

    float s[ODIM];
#pragma unroll
    for (int o = 0; o < ODIM; ++o) s[o] = 0.f;

    for (int i = 0; i < 3; ++i) {
        int pi = h - i;
        if ((unsigned)pi >= HO) continue;
        for (int j = 0; j < 3; ++j) {
            int pj = w - j;
            if ((unsigned)pj >= HO) continue;
            int kk = c * 9 + i * 3 + j;
            const float* tp = T + (size_t)kk * ODIM * LDIM + pi * HO + pj;
#pragma unroll
            for (int o = 0; o < ODIM; ++o) s[o] += tp[(size_t)o * LDIM];
        }
    }
#pragma unroll
    for (int o = 0; o < ODIM; ++o) S[o * CHW + idx] = s[o];
}

// ---------------------------------------------------------------------------
// K3: out[b][o] = sum_chw x[b][chw] * S[o][chw]; 2 images/block, 256 blocks.
// ---------------------------------------------------------------------------
__global__ __launch_bounds__(256)
void out_gemm_kernel(const float* __restrict__ X,
                     const float* __restrict__ S,
                     float* __restrict__ out) {
    const int b0  = blockIdx.x * 2;
    const int tid = threadIdx.x;
    const int NV  = CHW / 4;   // 3072
    const float4* X0 = reinterpret_cast<const float4*>(X) + (size_t)b0 * NV;
    const float4* X1 = X0 + NV;
    const float4* S4 = reinterpret_cast<const float4*>(S);

    float acc0[ODIM], acc1[ODIM];
#pragma unroll
    for (int o = 0; o < ODIM; ++o) { acc0[o] = 0.f; acc1[o] = 0.f; }

    for (int i = tid; i < NV; i += 256) {
        float4 a = X0[i];
        float4 b = X1[i];
#pragma unroll
        for (int o = 0; o < ODIM; ++o) {
            float4 sv = S4[(size_t)o * NV + i];
            acc0[o] += a.x * sv.x + a.y * sv.y + a.z * sv.z + a.w * sv.w;
            acc1[o] += b.x * sv.x + b.y * sv.y + b.z * sv.z + b.w * sv.w;
        }
    }

#pragma unroll
    for (int o = 0; o < ODIM; ++o) {
        float s0 = acc0[o], s1 = acc1[o];
        for (int off = 32; off > 0; off >>= 1) {
            s0 += __shfl_down(s0, off, 64);
            s1 += __shfl_down(s1, off, 64);
        }
        acc0[o] = s0; acc1[o] = s1;
    }

    __shared__ float red[4][2 * ODIM];
    int wave = tid >> 6;
    int lane = tid & 63;
    if (lane == 0) {
#pragma unroll
        for (int o = 0; o < ODIM; ++o) {
            red[wave][o] = acc0[o];
            red[wave][ODIM + o] = acc1[o];
        }
    }
    __syncthreads();
    if (tid < 2 * ODIM) {
        float tsum = red[0][tid] + red[1][tid] + red[2][tid] + red[3][tid];
        int bt = tid / ODIM;
        int o  = tid - bt * ODIM;
        out[(size_t)(b0 + bt) * ODIM + o] = tsum;
    }
}

extern "C" void kernel_launch(void* const* d_in, const int* in_sizes, int n_in,
                              void* d_out, int out_size, void* d_ws, size_t ws_size,
                              hipStream_t stream) {
    const float* x = (const float*)d_in[0];   // (512, 3, 64, 64)
    const float* G = (const float*)d_in[1];   // (512, 3844)
    const float* v = (const float*)d_in[2];   // (512, 27, 10)
    const float* w = (const float*)d_in[3];   // (512, 27, 10)
    float* out = (float*)d_out;               // (512, 10)

    float* T   = (float*)d_ws;                       // 270*3844 f = 4.15 MB
    float* S   = T + (size_t)KO * LDIM;              // 10*12288 f = 0.49 MB
    float* pdY = S + (size_t)ODIM * CHW;             // 16*512*24 f = 0.79 MB

    pd_kernel<<<(NG * M_NEUR * PDS + 255) / 256, 256, 0, stream>>>(v, w, pdY);

    t_gemm_kernel<<<1024, 256, 0, stream>>>(G, pdY, T);

    fold_kernel<<<CHW / 256, 256, 0, stream>>>(T, S);

    out_gemm_kernel<<<BATCH / 2, 256, 0, stream>>>(x, S, out);
}